// Round 1
// baseline (475.651 us; speedup 1.0000x reference)
//
#include <hip/hip_runtime.h>

// Fused ReconstructionHead: h = x[:, :-1] @ W1^T + b1; LayerNorm*gamma+beta;
// relu; out[b,t] = dot(h, Wout[t]) + bout[t].  M = 131072 rows, K = N = 512.
//
// R3 changes vs R2 (175 us kernel, MfmaUtil 16%, 1.15e7 LDS bank conflicts):
//  - double-buffered As/Bs + guide's minimum-2-phase pipeline: stage(c+1)
//    issued BEFORE compute(c), single __syncthreads()/chunk. B-DMA + A
//    prefetch latency now hides under frag reads + MFMA (was fully exposed
//    between two barriers on a single buffer).
//  - B LDS layout swizzled at 16-B-unit granularity:
//    P(row,q) = (row&7) + 8q + 32*(row>>3) within each 16-row band.
//    Realized by pre-swizzling the per-lane *global* DMA source (LDS dest
//    stays linear, as global_load_lds requires); reads use the matching
//    swizzled base. Kills the 8-way bank conflict of the old 64B-stride
//    row-major B reads (dominant LDS traffic).
//  - __launch_bounds__(512,4): pin <=128 unified V+A regs (2 blocks/CU).

#define DIN     512
#define BK      32
#define MT      64            // rows per block
#define THREADS 512           // 8 waves
#define NCHUNK  (DIN / BK)    // 16
#define ASTR    40            // A row stride in shorts (32 + 8 pad; VALU-written)
#define AS_SZ   (MT * ASTR)   // 2560 shorts per A buffer
#define BS_SZ   (DIN * BK)    // 16384 shorts per B buffer (32 KB), unit-swizzled
#define BANDS   (BK * 16)     // 512 shorts per 16-row band

typedef __attribute__((ext_vector_type(8))) short bf16x8;
typedef __attribute__((ext_vector_type(4))) float f32x4;

__device__ __forceinline__ short f2bf(float f) {
    unsigned u = __float_as_uint(f);
    u = u + 0x7fffu + ((u >> 16) & 1u);   // RNE
    return (short)(u >> 16);
}

__device__ __forceinline__ void gload_lds16(const void* g, void* l) {
    __builtin_amdgcn_global_load_lds(
        (const __attribute__((address_space(1))) unsigned int*)g,
        (__attribute__((address_space(3))) unsigned int*)l,
        16, 0, 0);
}

__global__ void cvt_w1_kernel(const float* __restrict__ w, short* __restrict__ o) {
    int i = blockIdx.x * blockDim.x + threadIdx.x;   // 65536 threads, 4 elems each
    float4 v = ((const float4*)w)[i];
    short4 s;
    s.x = f2bf(v.x); s.y = f2bf(v.y); s.z = f2bf(v.z); s.w = f2bf(v.w);
    ((short4*)o)[i] = s;
}

// fallback staging (no workspace): fp32 W1 -> bf16 via VALU, swizzled layout.
// thread tid owns logical row tid (band tid>>4, row-in-band tid&15), 4 units.
__device__ __forceinline__ void stage_b_fallback(short* dstBuf, const float* W1f,
                                                 int c, int tid) {
    const float* src = W1f + (size_t)tid * DIN + c * BK;
    const int band = tid >> 4, rr = tid & 15;
    short* dstband = dstBuf + band * BANDS;
#pragma unroll
    for (int p = 0; p < 4; ++p) {
        float4 v0 = *(const float4*)(src + p * 8);
        float4 v1 = *(const float4*)(src + p * 8 + 4);
        int P = (rr & 7) + 8 * p + ((rr >> 3) << 5);
        short* d = dstband + P * 8;
        short4 s0, s1;
        s0.x = f2bf(v0.x); s0.y = f2bf(v0.y); s0.z = f2bf(v0.z); s0.w = f2bf(v0.w);
        s1.x = f2bf(v1.x); s1.y = f2bf(v1.y); s1.z = f2bf(v1.z); s1.w = f2bf(v1.w);
        *(short4*)d = s0;
        *(short4*)(d + 4) = s1;
    }
}

template<bool WS>
__global__ __launch_bounds__(THREADS, 4)
void fused_head_kernel(const float* __restrict__ x,
                       const float* __restrict__ W1f,
                       const short* __restrict__ W1h,
                       const float* __restrict__ b1,
                       const float* __restrict__ gamma,
                       const float* __restrict__ beta,
                       const float* __restrict__ Wout,
                       const float* __restrict__ bout,
                       float* __restrict__ out) {
    __shared__ __align__(16) short As[2][AS_SZ];    // 10240 B
    __shared__ __align__(16) short Bs[2][BS_SZ];    // 65536 B
    __shared__ float redS[MT][4];
    __shared__ float redQ[MT][4];
    __shared__ float meanA[MT];
    __shared__ float rstdA[MT];

    const int tid  = threadIdx.x;
    const int w    = tid >> 6;        // wave 0..7
    const int lane = tid & 63;
    const int q    = lane >> 4;       // quad 0..3
    const int l15  = lane & 15;
    const int rg   = w >> 2;          // row group 0..1 (rows rg*32 .. +32)
    const int cg   = w & 3;           // col group 0..3 (cols cg*128 .. +128)

    const int m0 = blockIdx.x * MT;
    const int bb = m0 >> 9;           // batch index
    const int t0 = m0 & 511;          // first t of this block
    const float* xbase = x + (size_t)(bb * 513 + t0) * DIN;

    // A staging map: 512 threads cover 64 rows x 32 k fp32 (one float4 each)
    const int ar = tid >> 3;          // row 0..63
    const int ak = (tid & 7) * 4;     // k offset (4 floats)

    // B DMA swizzled source map. Wave w stages rows [w*64, w*64+64) as 4
    // instrs j, each a 16-row band -> 1024 B linear LDS. Lane i writes
    // physical unit i; it must fetch logical (row_in_band, q) = P^-1(i):
    //   row_in_band = (i&7) + 8*(i>>5),  q = (i>>3)&3
    const int brow = (lane & 7) + ((lane >> 5) << 3);
    const int bq   = (lane >> 3) & 3;
    const short* bG = W1h + (size_t)(w * 64 + brow) * DIN + bq * 8;

    // B frag read base: lane (q,l15) reads unit P(l15,q) of band cg*8 + tj
    const int bOff = cg * (8 * BANDS)
                   + ((l15 & 7) + 8 * q + ((l15 >> 3) << 5)) * 8;

    f32x4 acc[2][8];
#pragma unroll
    for (int i = 0; i < 2; ++i)
#pragma unroll
        for (int j = 0; j < 8; ++j)
            acc[i][j] = (f32x4){0.f, 0.f, 0.f, 0.f};

    // ---------------- prologue: stage chunk 0 into buf 0 ----------------
    float4 aReg = *(const float4*)(xbase + ar * DIN + ak);
    if (WS) {
#pragma unroll
        for (int j = 0; j < 4; ++j)
            gload_lds16(bG + (size_t)(j * 16) * DIN,
                        &Bs[0][w * (4 * BANDS) + j * BANDS]);
    } else {
        stage_b_fallback(Bs[0], W1f, 0, tid);
    }
    {
        short4 a4;
        a4.x = f2bf(aReg.x); a4.y = f2bf(aReg.y);
        a4.z = f2bf(aReg.z); a4.w = f2bf(aReg.w);
        *(short4*)(&As[0][ar * ASTR + ak]) = a4;
    }
    aReg = *(const float4*)(xbase + ar * DIN + BK + ak);   // A(1)
    __syncthreads();

    // ---------------- main loop: one barrier per chunk ----------------
    for (int c = 0; c < NCHUNK; ++c) {
        const int cur = c & 1, nxt = cur ^ 1;

        // stage chunk c+1 into buf nxt (issued BEFORE compute of chunk c)
        if (c + 1 < NCHUNK) {
            if (WS) {
#pragma unroll
                for (int j = 0; j < 4; ++j)
                    gload_lds16(bG + (size_t)(j * 16) * DIN + (c + 1) * BK,
                                &Bs[nxt][w * (4 * BANDS) + j * BANDS]);
            } else {
                stage_b_fallback(Bs[nxt], W1f, c + 1, tid);
            }
            short4 a4;
            a4.x = f2bf(aReg.x); a4.y = f2bf(aReg.y);
            a4.z = f2bf(aReg.z); a4.w = f2bf(aReg.w);
            *(short4*)(&As[nxt][ar * ASTR + ak]) = a4;
        }
        if (c + 2 < NCHUNK)
            aReg = *(const float4*)(xbase + ar * DIN + (c + 2) * BK + ak);

        // compute chunk c from buf cur
        const short* Ap = &As[cur][(rg * 32 + l15) * ASTR + q * 8];
        bf16x8 af0 = *(const bf16x8*)Ap;
        bf16x8 af1 = *(const bf16x8*)(Ap + 16 * ASTR);
        const short* Bp = &Bs[cur][bOff];
        {
            bf16x8 bfr[4];
#pragma unroll
            for (int tj = 0; tj < 4; ++tj)
                bfr[tj] = *(const bf16x8*)(Bp + tj * BANDS);
#pragma unroll
            for (int tj = 0; tj < 4; ++tj) {
                acc[0][tj] = __builtin_amdgcn_mfma_f32_16x16x32_bf16(
                    af0, bfr[tj], acc[0][tj], 0, 0, 0);
                acc[1][tj] = __builtin_amdgcn_mfma_f32_16x16x32_bf16(
                    af1, bfr[tj], acc[1][tj], 0, 0, 0);
            }
        }
        {
            bf16x8 bfr[4];
#pragma unroll
            for (int tj = 0; tj < 4; ++tj)
                bfr[tj] = *(const bf16x8*)(Bp + (tj + 4) * BANDS);
#pragma unroll
            for (int tj = 0; tj < 4; ++tj) {
                acc[0][tj + 4] = __builtin_amdgcn_mfma_f32_16x16x32_bf16(
                    af0, bfr[tj], acc[0][tj + 4], 0, 0, 0);
                acc[1][tj + 4] = __builtin_amdgcn_mfma_f32_16x16x32_bf16(
                    af1, bfr[tj], acc[1][tj + 4], 0, 0, 0);
            }
        }
        __syncthreads();   // drains vmcnt (next-chunk DMA + aReg) + lgkmcnt
    }

    // ================= epilogue =================
    float b1v[8], gv[8], bv[8];
    const int cb = cg * 128 + l15;
#pragma unroll
    for (int tj = 0; tj < 8; ++tj) {
        int col = cb + tj * 16;
        b1v[tj] = b1[col];
        gv[tj]  = gamma[col];
        bv[tj]  = beta[col];
    }

    // pass 1: row sums / sumsq.  C layout: col = l15 (within 16-col tile tj),
    // row = rg*32 + ti*16 + q*4 + r.
#pragma unroll
    for (int ti = 0; ti < 2; ++ti)
#pragma unroll
        for (int r = 0; r < 4; ++r) {
            int row = rg * 32 + ti * 16 + q * 4 + r;
            float s = 0.f, s2 = 0.f;
#pragma unroll
            for (int tj = 0; tj < 8; ++tj) {
                float v = acc[ti][tj][r] + b1v[tj];
                s += v; s2 += v * v;
            }
#pragma unroll
            for (int m = 1; m < 16; m <<= 1) {
                s  += __shfl_xor(s,  m, 64);
                s2 += __shfl_xor(s2, m, 64);
            }
            if (l15 == 0) { redS[row][cg] = s; redQ[row][cg] = s2; }
        }
    __syncthreads();
    if (tid < MT) {
        float s  = redS[tid][0] + redS[tid][1] + redS[tid][2] + redS[tid][3];
        float s2 = redQ[tid][0] + redQ[tid][1] + redQ[tid][2] + redQ[tid][3];
        float mean = s * (1.f / DIN);
        float var  = s2 * (1.f / DIN) - mean * mean;
        meanA[tid] = mean;
        rstdA[tid] = rsqrtf(fmaxf(var, 0.f) + 1e-5f);
    }
    __syncthreads();

    // pass 2: normalize + relu + dot with Wout[t]
#pragma unroll
    for (int ti = 0; ti < 2; ++ti)
#pragma unroll
        for (int r = 0; r < 4; ++r) {
            int row = rg * 32 + ti * 16 + q * 4 + r;
            float mean = meanA[row], rs = rstdA[row];
            const float* wrow = Wout + (size_t)(t0 + row) * DIN + cb;
            float s = 0.f;
#pragma unroll
            for (int tj = 0; tj < 8; ++tj) {
                float v = acc[ti][tj][r] + b1v[tj];
                v = (v - mean) * rs * gv[tj] + bv[tj];
                v = fmaxf(v, 0.f);
                s += v * wrow[tj * 16];
            }
#pragma unroll
            for (int m = 1; m < 16; m <<= 1)
                s += __shfl_xor(s, m, 64);
            if (l15 == 0) redS[row][cg] = s;
        }
    __syncthreads();
    if (tid < MT)
        out[m0 + tid] = redS[tid][0] + redS[tid][1] + redS[tid][2] + redS[tid][3]
                        + bout[t0 + tid];
}

extern "C" void kernel_launch(void* const* d_in, const int* in_sizes, int n_in,
                              void* d_out, int out_size, void* d_ws, size_t ws_size,
                              hipStream_t stream) {
    const float* x     = (const float*)d_in[0];
    const float* W1    = (const float*)d_in[1];
    const float* b1    = (const float*)d_in[2];
    const float* gamma = (const float*)d_in[3];
    const float* beta  = (const float*)d_in[4];
    const float* Wout  = (const float*)d_in[5];
    const float* bout  = (const float*)d_in[6];
    float* out = (float*)d_out;

    const int M = 256 * 512;
    dim3 grid(M / MT), block(THREADS);

    if (ws_size >= (size_t)(DIN * DIN) * sizeof(short)) {
        short* W1h = (short*)d_ws;
        cvt_w1_kernel<<<DIN * DIN / (256 * 4), 256, 0, stream>>>(W1, W1h);
        fused_head_kernel<true><<<grid, block, 0, stream>>>(
            x, W1, W1h, b1, gamma, beta, Wout, bout, out);
    } else {
        fused_head_kernel<false><<<grid, block, 0, stream>>>(
            x, W1, nullptr, b1, gamma, beta, Wout, bout, out);
    }
}

// Round 2
// 440.928 us; speedup vs baseline: 1.0787x; 1.0787x over previous
//
#include <hip/hip_runtime.h>

// Fused ReconstructionHead: h = x[:, :-1] @ W1^T + b1; LayerNorm*gamma+beta;
// relu; out[b,t] = dot(h, Wout[t]) + bout[t].  M = 131072 rows, K = N = 512.
//
// R4 changes vs R3 (218 us, regression from R2's 175):
//  - THEORY: R3's pre-swizzled DMA source put adjacent lanes 1024 B apart,
//    breaking adjacent-lane coalescing of global_load_lds -> 4x L2 request
//    rate -> staging became critical path. Conflict win (1.15e7 -> 3.1e6)
//    was real but smaller.
//  - New swizzle P(row,q) = row*4 + (q ^ ((row>>1)&3)): each aligned 4-lane
//    quad still sources ONE contiguous 64-B row segment (permuted within),
//    so coalescing is preserved; 16-lane read phase hits all 8 bank-groups
//    exactly 2x -> 2-way = free.
//  - MT=128, THREADS=1024 (16 waves, wave tile 32x128, acc[2][8] unchanged):
//    B/W1 staging per block is fixed at 0.5 MB (LayerNorm needs all 512
//    cols), so doubling rows/block halves staging per unit of MFMA work.
//    LDS 89 KB double-buffered -> 1 block/CU, 16 waves (~50% occupancy).
//  - Keep single-barrier 2-phase loop (stage c+1 issued before compute c).

#define DIN     512
#define BK      32
#define MT      128           // rows per block
#define THREADS 1024          // 16 waves
#define NCHUNK  (DIN / BK)    // 16
#define ASTR    40            // A row stride in shorts (32 + 8 pad; VALU-written)
#define AS_SZ   (MT * ASTR)   // 5120 shorts per A buffer
#define BS_SZ   (DIN * BK)    // 16384 shorts per B buffer (32 KB), unit-swizzled
#define BANDS   (BK * 16)     // 512 shorts per 16-row band

typedef __attribute__((ext_vector_type(8))) short bf16x8;
typedef __attribute__((ext_vector_type(4))) float f32x4;

__device__ __forceinline__ short f2bf(float f) {
    unsigned u = __float_as_uint(f);
    u = u + 0x7fffu + ((u >> 16) & 1u);   // RNE
    return (short)(u >> 16);
}

__device__ __forceinline__ void gload_lds16(const void* g, void* l) {
    __builtin_amdgcn_global_load_lds(
        (const __attribute__((address_space(1))) unsigned int*)g,
        (__attribute__((address_space(3))) unsigned int*)l,
        16, 0, 0);
}

__global__ void cvt_w1_kernel(const float* __restrict__ w, short* __restrict__ o) {
    int i = blockIdx.x * blockDim.x + threadIdx.x;   // 65536 threads, 4 elems each
    float4 v = ((const float4*)w)[i];
    short4 s;
    s.x = f2bf(v.x); s.y = f2bf(v.y); s.z = f2bf(v.z); s.w = f2bf(v.w);
    ((short4*)o)[i] = s;
}

// fallback staging (no workspace): fp32 W1 -> bf16 via VALU, swizzled layout.
// threads 0..511 each own logical row tid (band tid>>4, row-in-band tid&15).
__device__ __forceinline__ void stage_b_fallback(short* dstBuf, const float* W1f,
                                                 int c, int tid) {
    if (tid >= DIN) return;
    const float* src = W1f + (size_t)tid * DIN + c * BK;
    const int band = tid >> 4, rr = tid & 15;
    short* dstband = dstBuf + band * BANDS;
#pragma unroll
    for (int q = 0; q < 4; ++q) {
        float4 v0 = *(const float4*)(src + q * 8);
        float4 v1 = *(const float4*)(src + q * 8 + 4);
        int P = rr * 4 + (q ^ ((rr >> 1) & 3));
        short* d = dstband + P * 8;
        short4 s0, s1;
        s0.x = f2bf(v0.x); s0.y = f2bf(v0.y); s0.z = f2bf(v0.z); s0.w = f2bf(v0.w);
        s1.x = f2bf(v1.x); s1.y = f2bf(v1.y); s1.z = f2bf(v1.z); s1.w = f2bf(v1.w);
        *(short4*)d = s0;
        *(short4*)(d + 4) = s1;
    }
}

template<bool WS>
__global__ __launch_bounds__(THREADS, 4)
void fused_head_kernel(const float* __restrict__ x,
                       const float* __restrict__ W1f,
                       const short* __restrict__ W1h,
                       const float* __restrict__ b1,
                       const float* __restrict__ gamma,
                       const float* __restrict__ beta,
                       const float* __restrict__ Wout,
                       const float* __restrict__ bout,
                       float* __restrict__ out) {
    __shared__ __align__(16) short As[2][AS_SZ];    // 20480 B
    __shared__ __align__(16) short Bs[2][BS_SZ];    // 65536 B
    __shared__ float redS[MT][4];
    __shared__ float redQ[MT][4];
    __shared__ float meanA[MT];
    __shared__ float rstdA[MT];

    const int tid  = threadIdx.x;
    const int w    = tid >> 6;        // wave 0..15
    const int lane = tid & 63;
    const int q    = lane >> 4;       // quad 0..3
    const int l15  = lane & 15;
    const int rg   = w >> 2;          // row group 0..3 (rows rg*32 .. +32)
    const int cg   = w & 3;           // col group 0..3 (cols cg*128 .. +128)

    const int m0 = blockIdx.x * MT;
    const int bb = m0 >> 9;           // batch index
    const int t0 = m0 & 511;          // first t of this block (0|128|256|384)
    const float* xbase = x + (size_t)(bb * 513 + t0) * DIN;

    // A staging map: 1024 threads cover 128 rows x 32 k fp32 (one float4 each)
    const int ar = tid >> 3;          // row 0..127
    const int ak = (tid & 7) * 4;     // k offset (4 floats)

    // B DMA map. Wave w stages rows [w*32, w*32+32) = bands 2w, 2w+1, as 2
    // instrs j, each a 16-row band -> 1024 B linear LDS. Lane i writes
    // physical unit i; inverse of P(row,q)=row*4+(q^((row>>1)&3)) is
    //   row_in_band = i>>2,  q = (i&3) ^ ((i>>3)&3)
    // -> each aligned lane-quad reads ONE contiguous 64-B row segment.
    const int brow = lane >> 2;
    const int bq   = (lane & 3) ^ ((lane >> 3) & 3);
    const short* bG = W1h + (size_t)(w * 32 + brow) * DIN + bq * 8;

    // B frag read base: lane (q,l15) reads unit P(l15,q) of band cg*8 + tj.
    // Per 16-lane phase: unit%8 covers 0..7 exactly twice -> 2-way = free.
    const int bOff = cg * (8 * BANDS)
                   + (l15 * 4 + (q ^ ((l15 >> 1) & 3))) * 8;

    f32x4 acc[2][8];
#pragma unroll
    for (int i = 0; i < 2; ++i)
#pragma unroll
        for (int j = 0; j < 8; ++j)
            acc[i][j] = (f32x4){0.f, 0.f, 0.f, 0.f};

    // ---------------- prologue: stage chunk 0 into buf 0 ----------------
    float4 aReg = *(const float4*)(xbase + ar * DIN + ak);
    if (WS) {
#pragma unroll
        for (int j = 0; j < 2; ++j)
            gload_lds16(bG + (size_t)(j * 16) * DIN,
                        &Bs[0][w * (2 * BANDS) + j * BANDS]);
    } else {
        stage_b_fallback(Bs[0], W1f, 0, tid);
    }
    {
        short4 a4;
        a4.x = f2bf(aReg.x); a4.y = f2bf(aReg.y);
        a4.z = f2bf(aReg.z); a4.w = f2bf(aReg.w);
        *(short4*)(&As[0][ar * ASTR + ak]) = a4;
    }
    aReg = *(const float4*)(xbase + ar * DIN + BK + ak);   // A(1)
    __syncthreads();

    // ---------------- main loop: one barrier per chunk ----------------
    for (int c = 0; c < NCHUNK; ++c) {
        const int cur = c & 1, nxt = cur ^ 1;

        // stage chunk c+1 into buf nxt (issued BEFORE compute of chunk c)
        if (c + 1 < NCHUNK) {
            if (WS) {
#pragma unroll
                for (int j = 0; j < 2; ++j)
                    gload_lds16(bG + (size_t)(j * 16) * DIN + (c + 1) * BK,
                                &Bs[nxt][w * (2 * BANDS) + j * BANDS]);
            } else {
                stage_b_fallback(Bs[nxt], W1f, c + 1, tid);
            }
            short4 a4;
            a4.x = f2bf(aReg.x); a4.y = f2bf(aReg.y);
            a4.z = f2bf(aReg.z); a4.w = f2bf(aReg.w);
            *(short4*)(&As[nxt][ar * ASTR + ak]) = a4;
        }
        if (c + 2 < NCHUNK)
            aReg = *(const float4*)(xbase + ar * DIN + (c + 2) * BK + ak);

        // compute chunk c from buf cur
        const short* Ap = &As[cur][(rg * 32 + l15) * ASTR + q * 8];
        bf16x8 af0 = *(const bf16x8*)Ap;
        bf16x8 af1 = *(const bf16x8*)(Ap + 16 * ASTR);
        const short* Bp = &Bs[cur][bOff];
        {
            bf16x8 bfr[4];
#pragma unroll
            for (int tj = 0; tj < 4; ++tj)
                bfr[tj] = *(const bf16x8*)(Bp + tj * BANDS);
#pragma unroll
            for (int tj = 0; tj < 4; ++tj) {
                acc[0][tj] = __builtin_amdgcn_mfma_f32_16x16x32_bf16(
                    af0, bfr[tj], acc[0][tj], 0, 0, 0);
                acc[1][tj] = __builtin_amdgcn_mfma_f32_16x16x32_bf16(
                    af1, bfr[tj], acc[1][tj], 0, 0, 0);
            }
        }
        {
            bf16x8 bfr[4];
#pragma unroll
            for (int tj = 0; tj < 4; ++tj)
                bfr[tj] = *(const bf16x8*)(Bp + (tj + 4) * BANDS);
#pragma unroll
            for (int tj = 0; tj < 4; ++tj) {
                acc[0][tj + 4] = __builtin_amdgcn_mfma_f32_16x16x32_bf16(
                    af0, bfr[tj], acc[0][tj + 4], 0, 0, 0);
                acc[1][tj + 4] = __builtin_amdgcn_mfma_f32_16x16x32_bf16(
                    af1, bfr[tj], acc[1][tj + 4], 0, 0, 0);
            }
        }
        __syncthreads();   // drains vmcnt (next-chunk DMA + aReg) + lgkmcnt
    }

    // ================= epilogue =================
    float b1v[8], gv[8], bv[8];
    const int cb = cg * 128 + l15;
#pragma unroll
    for (int tj = 0; tj < 8; ++tj) {
        int col = cb + tj * 16;
        b1v[tj] = b1[col];
        gv[tj]  = gamma[col];
        bv[tj]  = beta[col];
    }

    // pass 1: row sums / sumsq.  C layout: col = l15 (within 16-col tile tj),
    // row = rg*32 + ti*16 + q*4 + r.
#pragma unroll
    for (int ti = 0; ti < 2; ++ti)
#pragma unroll
        for (int r = 0; r < 4; ++r) {
            int row = rg * 32 + ti * 16 + q * 4 + r;
            float s = 0.f, s2 = 0.f;
#pragma unroll
            for (int tj = 0; tj < 8; ++tj) {
                float v = acc[ti][tj][r] + b1v[tj];
                s += v; s2 += v * v;
            }
#pragma unroll
            for (int m = 1; m < 16; m <<= 1) {
                s  += __shfl_xor(s,  m, 64);
                s2 += __shfl_xor(s2, m, 64);
            }
            if (l15 == 0) { redS[row][cg] = s; redQ[row][cg] = s2; }
        }
    __syncthreads();
    if (tid < MT) {
        float s  = redS[tid][0] + redS[tid][1] + redS[tid][2] + redS[tid][3];
        float s2 = redQ[tid][0] + redQ[tid][1] + redQ[tid][2] + redQ[tid][3];
        float mean = s * (1.f / DIN);
        float var  = s2 * (1.f / DIN) - mean * mean;
        meanA[tid] = mean;
        rstdA[tid] = rsqrtf(fmaxf(var, 0.f) + 1e-5f);
    }
    __syncthreads();

    // pass 2: normalize + relu + dot with Wout[t]
#pragma unroll
    for (int ti = 0; ti < 2; ++ti)
#pragma unroll
        for (int r = 0; r < 4; ++r) {
            int row = rg * 32 + ti * 16 + q * 4 + r;
            float mean = meanA[row], rs = rstdA[row];
            const float* wrow = Wout + (size_t)(t0 + row) * DIN + cb;
            float s = 0.f;
#pragma unroll
            for (int tj = 0; tj < 8; ++tj) {
                float v = acc[ti][tj][r] + b1v[tj];
                v = (v - mean) * rs * gv[tj] + bv[tj];
                v = fmaxf(v, 0.f);
                s += v * wrow[tj * 16];
            }
#pragma unroll
            for (int m = 1; m < 16; m <<= 1)
                s += __shfl_xor(s, m, 64);
            if (l15 == 0) redS[row][cg] = s;
        }
    __syncthreads();
    if (tid < MT)
        out[m0 + tid] = redS[tid][0] + redS[tid][1] + redS[tid][2] + redS[tid][3]
                        + bout[t0 + tid];
}

extern "C" void kernel_launch(void* const* d_in, const int* in_sizes, int n_in,
                              void* d_out, int out_size, void* d_ws, size_t ws_size,
                              hipStream_t stream) {
    const float* x     = (const float*)d_in[0];
    const float* W1    = (const float*)d_in[1];
    const float* b1    = (const float*)d_in[2];
    const float* gamma = (const float*)d_in[3];
    const float* beta  = (const float*)d_in[4];
    const float* Wout  = (const float*)d_in[5];
    const float* bout  = (const float*)d_in[6];
    float* out = (float*)d_out;

    const int M = 256 * 512;
    dim3 grid(M / MT), block(THREADS);

    if (ws_size >= (size_t)(DIN * DIN) * sizeof(short)) {
        short* W1h = (short*)d_ws;
        cvt_w1_kernel<<<DIN * DIN / (256 * 4), 256, 0, stream>>>(W1, W1h);
        fused_head_kernel<true><<<grid, block, 0, stream>>>(
            x, W1, W1h, b1, gamma, beta, Wout, bout, out);
    } else {
        fused_head_kernel<false><<<grid, block, 0, stream>>>(
            x, W1, nullptr, b1, gamma, beta, Wout, bout, out);
    }
}

// Round 3
// 436.973 us; speedup vs baseline: 1.0885x; 1.0091x over previous
//
#include <hip/hip_runtime.h>

// Fused ReconstructionHead: h = x[:, :-1] @ W1^T + b1; LayerNorm*gamma+beta;
// relu; out[b,t] = dot(h, Wout[t]) + bout[t].  M = 131072 rows, K = N = 512.
//
// R5 = R3's resource config (MT=64, 512 thr, 78 KB LDS, 2 blocks/CU,
// spill-free: R3 showed WRITE_SIZE=512KB) + R4's coalescing-preserving
// swizzle + 2-phase single-barrier loop.
//  - R4 (MT=128/1024thr, 1 blk/CU) showed a ~60 B/thread scratch-spill
//    signature (WRITE 512KB->62MB, FETCH +32MB) and lost inter-block
//    overlap; revert those, keep its two wins:
//  - B swizzle P(row,q) = row*4 + (q ^ ((row>>1)&3)): DMA side, each
//    aligned 4-lane quad sources ONE contiguous 64-B row segment (coalesced,
//    fixing R3's 4x L2 request-rate bug); read side, each 16-lane phase hits
//    all 8 bank-groups exactly 2x -> conflict-free.
//  - 2-phase loop: stage(c+1) issued BEFORE compute(c), one barrier/chunk.
//    DMA latency hides under own compute + the co-resident block.

#define DIN     512
#define BK      32
#define MT      64            // rows per block
#define THREADS 512           // 8 waves
#define NCHUNK  (DIN / BK)    // 16
#define ASTR    40            // A row stride in shorts (32 + 8 pad; VALU-written)
#define AS_SZ   (MT * ASTR)   // 2560 shorts per A buffer
#define BS_SZ   (DIN * BK)    // 16384 shorts per B buffer (32 KB), unit-swizzled
#define BANDS   (BK * 16)     // 512 shorts per 16-row band

typedef __attribute__((ext_vector_type(8))) short bf16x8;
typedef __attribute__((ext_vector_type(4))) float f32x4;

__device__ __forceinline__ short f2bf(float f) {
    unsigned u = __float_as_uint(f);
    u = u + 0x7fffu + ((u >> 16) & 1u);   // RNE
    return (short)(u >> 16);
}

__device__ __forceinline__ void gload_lds16(const void* g, void* l) {
    __builtin_amdgcn_global_load_lds(
        (const __attribute__((address_space(1))) unsigned int*)g,
        (__attribute__((address_space(3))) unsigned int*)l,
        16, 0, 0);
}

__global__ void cvt_w1_kernel(const float* __restrict__ w, short* __restrict__ o) {
    int i = blockIdx.x * blockDim.x + threadIdx.x;   // 65536 threads, 4 elems each
    float4 v = ((const float4*)w)[i];
    short4 s;
    s.x = f2bf(v.x); s.y = f2bf(v.y); s.z = f2bf(v.z); s.w = f2bf(v.w);
    ((short4*)o)[i] = s;
}

// fallback staging (no workspace): fp32 W1 -> bf16 via VALU, swizzled layout.
// thread tid owns logical row tid (band tid>>4, row-in-band tid&15).
__device__ __forceinline__ void stage_b_fallback(short* dstBuf, const float* W1f,
                                                 int c, int tid) {
    const float* src = W1f + (size_t)tid * DIN + c * BK;
    const int band = tid >> 4, rr = tid & 15;
    short* dstband = dstBuf + band * BANDS;
#pragma unroll
    for (int q = 0; q < 4; ++q) {
        float4 v0 = *(const float4*)(src + q * 8);
        float4 v1 = *(const float4*)(src + q * 8 + 4);
        int P = rr * 4 + (q ^ ((rr >> 1) & 3));
        short* d = dstband + P * 8;
        short4 s0, s1;
        s0.x = f2bf(v0.x); s0.y = f2bf(v0.y); s0.z = f2bf(v0.z); s0.w = f2bf(v0.w);
        s1.x = f2bf(v1.x); s1.y = f2bf(v1.y); s1.z = f2bf(v1.z); s1.w = f2bf(v1.w);
        *(short4*)d = s0;
        *(short4*)(d + 4) = s1;
    }
}

template<bool WS>
__global__ __launch_bounds__(THREADS, 4)
void fused_head_kernel(const float* __restrict__ x,
                       const float* __restrict__ W1f,
                       const short* __restrict__ W1h,
                       const float* __restrict__ b1,
                       const float* __restrict__ gamma,
                       const float* __restrict__ beta,
                       const float* __restrict__ Wout,
                       const float* __restrict__ bout,
                       float* __restrict__ out) {
    __shared__ __align__(16) short As[2][AS_SZ];    // 10240 B
    __shared__ __align__(16) short Bs[2][BS_SZ];    // 65536 B
    __shared__ float redS[MT][4];
    __shared__ float redQ[MT][4];
    __shared__ float meanA[MT];
    __shared__ float rstdA[MT];

    const int tid  = threadIdx.x;
    const int w    = tid >> 6;        // wave 0..7
    const int lane = tid & 63;
    const int q    = lane >> 4;       // quad 0..3
    const int l15  = lane & 15;
    const int rg   = w >> 2;          // row group 0..1 (rows rg*32 .. +32)
    const int cg   = w & 3;           // col group 0..3 (cols cg*128 .. +128)

    const int m0 = blockIdx.x * MT;
    const int bb = m0 >> 9;           // batch index
    const int t0 = m0 & 511;          // first t of this block
    const float* xbase = x + (size_t)(bb * 513 + t0) * DIN;

    // A staging map: 512 threads cover 64 rows x 32 k fp32 (one float4 each)
    const int ar = tid >> 3;          // row 0..63
    const int ak = (tid & 7) * 4;     // k offset (4 floats)

    // B DMA map. Wave w stages rows [w*64, w*64+64) = bands 4w..4w+3, as 4
    // instrs j, each a 16-row band -> 1024 B linear LDS. Lane i writes
    // physical unit i; inverse of P(row,q)=row*4+(q^((row>>1)&3)) is
    //   row_in_band = i>>2,  q = (i&3) ^ ((i>>3)&3)
    // -> each aligned lane-quad reads ONE contiguous 64-B row segment.
    const int brow = lane >> 2;
    const int bq   = (lane & 3) ^ ((lane >> 3) & 3);
    const short* bG = W1h + (size_t)(w * 64 + brow) * DIN + bq * 8;

    // B frag read base: lane (q,l15) reads unit P(l15,q) of band cg*8 + tj.
    // Per 16-lane phase: unit%8 covers 0..7 exactly twice -> 2-way = free.
    const int bOff = cg * (8 * BANDS)
                   + (l15 * 4 + (q ^ ((l15 >> 1) & 3))) * 8;

    f32x4 acc[2][8];
#pragma unroll
    for (int i = 0; i < 2; ++i)
#pragma unroll
        for (int j = 0; j < 8; ++j)
            acc[i][j] = (f32x4){0.f, 0.f, 0.f, 0.f};

    // ---------------- prologue: stage chunk 0 into buf 0 ----------------
    float4 aReg = *(const float4*)(xbase + ar * DIN + ak);
    if (WS) {
#pragma unroll
        for (int j = 0; j < 4; ++j)
            gload_lds16(bG + (size_t)(j * 16) * DIN,
                        &Bs[0][w * (4 * BANDS) + j * BANDS]);
    } else {
        stage_b_fallback(Bs[0], W1f, 0, tid);
    }
    {
        short4 a4;
        a4.x = f2bf(aReg.x); a4.y = f2bf(aReg.y);
        a4.z = f2bf(aReg.z); a4.w = f2bf(aReg.w);
        *(short4*)(&As[0][ar * ASTR + ak]) = a4;
    }
    aReg = *(const float4*)(xbase + ar * DIN + BK + ak);   // A(1)
    __syncthreads();

    // ---------------- main loop: one barrier per chunk ----------------
    for (int c = 0; c < NCHUNK; ++c) {
        const int cur = c & 1, nxt = cur ^ 1;

        // stage chunk c+1 into buf nxt (issued BEFORE compute of chunk c)
        if (c + 1 < NCHUNK) {
            if (WS) {
#pragma unroll
            for (int j = 0; j < 4; ++j)
                gload_lds16(bG + (size_t)(j * 16) * DIN + (c + 1) * BK,
                            &Bs[nxt][w * (4 * BANDS) + j * BANDS]);
            } else {
                stage_b_fallback(Bs[nxt], W1f, c + 1, tid);
            }
            short4 a4;
            a4.x = f2bf(aReg.x); a4.y = f2bf(aReg.y);
            a4.z = f2bf(aReg.z); a4.w = f2bf(aReg.w);
            *(short4*)(&As[nxt][ar * ASTR + ak]) = a4;
        }
        if (c + 2 < NCHUNK)
            aReg = *(const float4*)(xbase + ar * DIN + (c + 2) * BK + ak);

        // compute chunk c from buf cur
        const short* Ap = &As[cur][(rg * 32 + l15) * ASTR + q * 8];
        bf16x8 af0 = *(const bf16x8*)Ap;
        bf16x8 af1 = *(const bf16x8*)(Ap + 16 * ASTR);
        const short* Bp = &Bs[cur][bOff];
        {
            bf16x8 bfr[4];
#pragma unroll
            for (int tj = 0; tj < 4; ++tj)
                bfr[tj] = *(const bf16x8*)(Bp + tj * BANDS);
#pragma unroll
            for (int tj = 0; tj < 4; ++tj) {
                acc[0][tj] = __builtin_amdgcn_mfma_f32_16x16x32_bf16(
                    af0, bfr[tj], acc[0][tj], 0, 0, 0);
                acc[1][tj] = __builtin_amdgcn_mfma_f32_16x16x32_bf16(
                    af1, bfr[tj], acc[1][tj], 0, 0, 0);
            }
        }
        {
            bf16x8 bfr[4];
#pragma unroll
            for (int tj = 0; tj < 4; ++tj)
                bfr[tj] = *(const bf16x8*)(Bp + (tj + 4) * BANDS);
#pragma unroll
            for (int tj = 0; tj < 4; ++tj) {
                acc[0][tj + 4] = __builtin_amdgcn_mfma_f32_16x16x32_bf16(
                    af0, bfr[tj], acc[0][tj + 4], 0, 0, 0);
                acc[1][tj + 4] = __builtin_amdgcn_mfma_f32_16x16x32_bf16(
                    af1, bfr[tj], acc[1][tj + 4], 0, 0, 0);
            }
        }
        __syncthreads();   // drains vmcnt (next-chunk DMA + aReg) + lgkmcnt
    }

    // ================= epilogue =================
    float b1v[8], gv[8], bv[8];
    const int cb = cg * 128 + l15;
#pragma unroll
    for (int tj = 0; tj < 8; ++tj) {
        int col = cb + tj * 16;
        b1v[tj] = b1[col];
        gv[tj]  = gamma[col];
        bv[tj]  = beta[col];
    }

    // pass 1: row sums / sumsq.  C layout: col = l15 (within 16-col tile tj),
    // row = rg*32 + ti*16 + q*4 + r.
#pragma unroll
    for (int ti = 0; ti < 2; ++ti)
#pragma unroll
        for (int r = 0; r < 4; ++r) {
            int row = rg * 32 + ti * 16 + q * 4 + r;
            float s = 0.f, s2 = 0.f;
#pragma unroll
            for (int tj = 0; tj < 8; ++tj) {
                float v = acc[ti][tj][r] + b1v[tj];
                s += v; s2 += v * v;
            }
#pragma unroll
            for (int m = 1; m < 16; m <<= 1) {
                s  += __shfl_xor(s,  m, 64);
                s2 += __shfl_xor(s2, m, 64);
            }
            if (l15 == 0) { redS[row][cg] = s; redQ[row][cg] = s2; }
        }
    __syncthreads();
    if (tid < MT) {
        float s  = redS[tid][0] + redS[tid][1] + redS[tid][2] + redS[tid][3];
        float s2 = redQ[tid][0] + redQ[tid][1] + redQ[tid][2] + redQ[tid][3];
        float mean = s * (1.f / DIN);
        float var  = s2 * (1.f / DIN) - mean * mean;
        meanA[tid] = mean;
        rstdA[tid] = rsqrtf(fmaxf(var, 0.f) + 1e-5f);
    }
    __syncthreads();

    // pass 2: normalize + relu + dot with Wout[t]
#pragma unroll
    for (int ti = 0; ti < 2; ++ti)
#pragma unroll
        for (int r = 0; r < 4; ++r) {
            int row = rg * 32 + ti * 16 + q * 4 + r;
            float mean = meanA[row], rs = rstdA[row];
            const float* wrow = Wout + (size_t)(t0 + row) * DIN + cb;
            float s = 0.f;
#pragma unroll
            for (int tj = 0; tj < 8; ++tj) {
                float v = acc[ti][tj][r] + b1v[tj];
                v = (v - mean) * rs * gv[tj] + bv[tj];
                v = fmaxf(v, 0.f);
                s += v * wrow[tj * 16];
            }
#pragma unroll
            for (int m = 1; m < 16; m <<= 1)
                s += __shfl_xor(s, m, 64);
            if (l15 == 0) redS[row][cg] = s;
        }
    __syncthreads();
    if (tid < MT)
        out[m0 + tid] = redS[tid][0] + redS[tid][1] + redS[tid][2] + redS[tid][3]
                        + bout[t0 + tid];
}

extern "C" void kernel_launch(void* const* d_in, const int* in_sizes, int n_in,
                              void* d_out, int out_size, void* d_ws, size_t ws_size,
                              hipStream_t stream) {
    const float* x     = (const float*)d_in[0];
    const float* W1    = (const float*)d_in[1];
    const float* b1    = (const float*)d_in[2];
    const float* gamma = (const float*)d_in[3];
    const float* beta  = (const float*)d_in[4];
    const float* Wout  = (const float*)d_in[5];
    const float* bout  = (const float*)d_in[6];
    float* out = (float*)d_out;

    const int M = 256 * 512;
    dim3 grid(M / MT), block(THREADS);

    if (ws_size >= (size_t)(DIN * DIN) * sizeof(short)) {
        short* W1h = (short*)d_ws;
        cvt_w1_kernel<<<DIN * DIN / (256 * 4), 256, 0, stream>>>(W1, W1h);
        fused_head_kernel<true><<<grid, block, 0, stream>>>(
            x, W1, W1h, b1, gamma, beta, Wout, bout, out);
    } else {
        fused_head_kernel<false><<<grid, block, 0, stream>>>(
            x, W1, nullptr, b1, gamma, beta, Wout, bout, out);
    }
}